// Round 7
// baseline (379.687 us; speedup 1.0000x reference)
//
#include <hip/hip_runtime.h>
#include <cmath>

#define BATCH 32
#define SEQLEN 512
#define NSAMP 1000
#define DMODEL 1024
#define NCHUNK 8

typedef __bf16 bf16x8_t __attribute__((ext_vector_type(8)));
typedef float f32x4_t __attribute__((ext_vector_type(4)));

__device__ __forceinline__ unsigned pack_bf2(float lo, float hi) {
    unsigned ulo = __float_as_uint(lo);
    unsigned uhi = __float_as_uint(hi);
    ulo = (ulo + 0x7fffu + ((ulo >> 16) & 1u)) >> 16;
    uhi = (uhi + 0x7fffu + ((uhi >> 16) & 1u)) & 0xffff0000u;
    return (ulo & 0xffffu) | uhi;
}

// TF log-uniform sampler expected-count, log-domain
__device__ __forceinline__ float log_expected_count(int id) {
    float idf = (float)id;
    float p = log1pf(1.0f / (idf + 1.0f)) * 0.09242316f; // 1/ln(50001)
    return logf(-expm1f(1000.0f * log1pf(-p)));
}

// async 16B global->LDS (dest = wave-uniform base + lane*16)
__device__ __forceinline__ void gl16(const void* g, void* l) {
    __builtin_amdgcn_global_load_lds(
        (const __attribute__((address_space(1))) unsigned int*)g,
        (__attribute__((address_space(3))) unsigned int*)l,
        16, 0, 0);
}

// ---- prep: fp32 true-logit dot + h->bf16 conversion ----
__global__ __launch_bounds__(256) void prep_kernel(
    const float* __restrict__ h, const int* __restrict__ labels,
    const float* __restrict__ W, const float* __restrict__ bias,
    unsigned short* __restrict__ hb, float* __restrict__ tlw)
{
    const int w = threadIdx.x >> 6, lane = threadIdx.x & 63;
    const int r = blockIdx.x * 4 + w;              // b*512+t
    const int lab = labels[r];
    const float4* hp = (const float4*)(h + (size_t)r * DMODEL);
    const float4* wp = (const float4*)(W + (size_t)lab * DMODEL);
    unsigned short* hdst = hb + (size_t)r * DMODEL;
    float s = 0.0f;
#pragma unroll
    for (int j = 0; j < 4; ++j) {
        float4 a = hp[lane + j * 64];
        float4 c = wp[lane + j * 64];
        s += a.x * c.x + a.y * c.y + a.z * c.z + a.w * c.w;
        uint2 u;
        u.x = pack_bf2(a.x, a.y);
        u.y = pack_bf2(a.z, a.w);
        *(uint2*)(hdst + (lane + j * 64) * 4) = u;
    }
#pragma unroll
    for (int off = 32; off > 0; off >>= 1) s += __shfl_xor(s, off, 64);
    if (lane == 0) tlw[r] = s + bias[lab] - log_expected_count(lab);
}

// ---- main: 512x128 tile (M=all rows of bb, N=128-sample chunk), BK=32 ----
// Minimal-traffic geometry: A (hb) read ONCE (33.5 MB total), each W row
// gathered ONCE (131 MB total). Grid = 32 bb x 8 chunks = 256 blocks.
// 8 waves as 4M x 2N; wave-tile 128x64; acc 8x4 f32x4 = 128 VGPR.
// Pipeline (R6 structure): per iter issue B[kt+1] regs (2 float4) then
// A[kt+1] gl16 (x4) -> vmcnt(6) [A[kt] landed] -> MFMA -> vmcnt(4)
// [B regs landed] -> pack+swizzled ds_write -> lgkm0 -> ONE barrier.
__global__ __launch_bounds__(512, 2) void sampled_softmax_main(
    const int* __restrict__ labels, const int* __restrict__ sids,
    const unsigned short* __restrict__ hb, const float* __restrict__ W,
    const float* __restrict__ bias,
    float* __restrict__ pm, float* __restrict__ pl)
{
    __shared__ __align__(16) unsigned short Ab[2][512 * 32];   // 64 KB
    __shared__ __align__(16) unsigned short Bb[2][128 * 32];   // 16 KB
    __shared__ int   sid_lds[128];
    __shared__ float adj_lds[128];
    __shared__ int   lab_lds[512];
    __shared__ float mpart[2][512];
    __shared__ float lpart[2][512];

    const int wg    = blockIdx.x;        // 0..255
    const int bb    = wg & 31;           // same-bb blocks share XCD (wg%8)
    const int chunk = wg >> 5;           // 0..7 (128 samples each)
    const int tid = threadIdx.x;
    const int wv  = tid >> 6, l = tid & 63;
    const int wr  = wv >> 1, wc = wv & 1;   // 4M x 2N wave grid
    const int lm  = l & 15,  q = l >> 4;
    const int rl4 = l >> 2,  cp = l & 3;

    {   // aux staging
        if (tid < 128) {
            const int s = chunk * 128 + tid;
            if (s < NSAMP) {
                const int sv = sids[bb * NSAMP + s];
                sid_lds[tid] = sv;
                adj_lds[tid] = bias[sv] - log_expected_count(sv);
            } else {
                sid_lds[tid] = -1;
                adj_lds[tid] = 0.0f;
            }
        }
        lab_lds[tid] = labels[bb * SEQLEN + tid];
    }

    // A staging: linear LDS dest, inverse-swizzled global source (rule #21).
    // gl16 #j of wave wv covers rows 64*wv + 16*j + rl4, LDS chunk pos cp;
    // global chunk = cp ^ s(row), s(r) = (r&3)^((r>>2)&3) = swzs (row mod 16 = rl4).
    const int swzs = (rl4 & 3) ^ ((rl4 >> 2) & 3);
    const int csA = (cp ^ swzs) * 8;
    const unsigned short* aSrc = hb + (size_t)(bb * SEQLEN + 64 * wv + rl4) * DMODEL + csA;

    // B staging (reg-gather): thread -> row = tid>>2 (0..127), kc = tid&3.
    // Loads global chunk kc of W[sids[row]]; writes LDS pos kc ^ s(row).
    const int brow = tid >> 2, bkc = tid & 3;
    int rbg = chunk * 128 + brow;
    if (rbg > NSAMP - 1) rbg = NSAMP - 1;              // clamp (masked in LSE)
    const float* wsrc = W + (size_t)sids[bb * NSAMP + rbg] * DMODEL + bkc * 8;
    const int sB = (brow & 3) ^ ((brow >> 2) & 3);
    const int bwoff = brow * 32 + (bkc ^ sB) * 8;

    float4 br0, br1;
#define LOAD_B(KT)                                                            \
    do {                                                                      \
        br0 = *(const float4*)(wsrc + (KT) * 32);                             \
        br1 = *(const float4*)(wsrc + (KT) * 32 + 4);                         \
    } while (0)

#define PACK_WRITE_B(BUF)                                                     \
    do {                                                                      \
        uint4 u;                                                              \
        u.x = pack_bf2(br0.x, br0.y);                                         \
        u.y = pack_bf2(br0.z, br0.w);                                         \
        u.z = pack_bf2(br1.x, br1.y);                                         \
        u.w = pack_bf2(br1.z, br1.w);                                         \
        *(uint4*)&Bb[BUF][bwoff] = u;                                         \
    } while (0)

#define STAGE_A(KT, BUF)                                                      \
    do {                                                                      \
        const size_t _adv = (size_t)(KT) * 32;                                \
        gl16(aSrc + _adv,                &Ab[BUF][(64 * wv     ) * 32]);      \
        gl16(aSrc + 16 * DMODEL + _adv,  &Ab[BUF][(64 * wv + 16) * 32]);      \
        gl16(aSrc + 32 * DMODEL + _adv,  &Ab[BUF][(64 * wv + 32) * 32]);      \
        gl16(aSrc + 48 * DMODEL + _adv,  &Ab[BUF][(64 * wv + 48) * 32]);      \
    } while (0)

    // fragment read offsets (swizzled, one K-sub per BK=32 tile)
    const int fswz = (lm & 3) ^ ((lm >> 2) & 3);
    const int ck = (q ^ fswz) * 8;
    int aoff[8], boff[4];
#pragma unroll
    for (int t = 0; t < 8; ++t) aoff[t] = (128 * wr + 16 * t + lm) * 32 + ck;
#pragma unroll
    for (int c = 0; c < 4; ++c) boff[c] = (64 * wc + 16 * c + lm) * 32 + ck;

    f32x4_t acc[8][4];
#pragma unroll
    for (int t = 0; t < 8; ++t)
#pragma unroll
        for (int c = 0; c < 4; ++c) acc[t][c] = (f32x4_t){0.f, 0.f, 0.f, 0.f};

    // prologue: tile 0 fully staged
    LOAD_B(0);
    __builtin_amdgcn_sched_barrier(0);
    STAGE_A(0, 0);
    asm volatile("s_waitcnt vmcnt(0)" ::: "memory");
    PACK_WRITE_B(0);
    asm volatile("s_waitcnt lgkmcnt(0)" ::: "memory");
    __builtin_amdgcn_s_barrier();

#pragma unroll
    for (int kt = 0; kt < 32; ++kt) {
        const int cur = kt & 1, nxt = cur ^ 1;
        if (kt + 1 < 32) {
            LOAD_B(kt + 1);                 // 2 vm-ops, then 4 gl16 (order pinned)
            __builtin_amdgcn_sched_barrier(0);
            STAGE_A(kt + 1, nxt);
            // 6 new outstanding; wait for prior iter's 4 A gl16 -> A[kt] landed
            asm volatile("s_waitcnt vmcnt(6)" ::: "memory");
        } else {
            asm volatile("s_waitcnt vmcnt(0)" ::: "memory");
        }

        const unsigned short* Ac = Ab[cur];
        const unsigned short* Bc = Bb[cur];
        bf16x8_t fa[8];
#pragma unroll
        for (int t = 0; t < 8; ++t) fa[t] = *(const bf16x8_t*)(Ac + aoff[t]);
        __builtin_amdgcn_s_setprio(1);
#pragma unroll
        for (int c = 0; c < 4; ++c) {
            bf16x8_t fb = *(const bf16x8_t*)(Bc + boff[c]);
#pragma unroll
            for (int t = 0; t < 8; ++t)
                acc[t][c] = __builtin_amdgcn_mfma_f32_16x16x32_bf16(fa[t], fb, acc[t][c], 0, 0, 0);
        }
        __builtin_amdgcn_s_setprio(0);

        if (kt + 1 < 32) {
            // the 2 B float4s (oldest of the 6) landed; 4 A gl16 stay in flight
            asm volatile("s_waitcnt vmcnt(4)" ::: "memory");
            PACK_WRITE_B(nxt);
            asm volatile("s_waitcnt lgkmcnt(0)" ::: "memory");
            __builtin_amdgcn_s_barrier();   // ONE barrier per iteration
        }
    }
#undef LOAD_B
#undef PACK_WRITE_B
#undef STAGE_A

    // epilogue: in-register partial LSE.
    // C layout: row = 128*wr + 16*t + 4*q + i, col = 64*wc + 16*c + lm
    float adjv[4]; int sidv[4]; bool cval[4];
#pragma unroll
    for (int c = 0; c < 4; ++c) {
        const int col = 64 * wc + 16 * c + lm;
        adjv[c] = adj_lds[col];
        sidv[c] = sid_lds[col];
        cval[c] = (chunk * 128 + col) < NSAMP;
    }
#pragma unroll
    for (int t = 0; t < 8; ++t) {
#pragma unroll
        for (int i = 0; i < 4; ++i) {
            const int r = 128 * wr + 16 * t + 4 * q + i;
            const int lab = lab_lds[r];
            float x[4]; bool ok[4];
            float m = -INFINITY;
#pragma unroll
            for (int c = 0; c < 4; ++c) {
                x[c] = acc[t][c][i] + adjv[c];
                ok[c] = cval[c] && (sidv[c] != lab);
                if (ok[c]) m = fmaxf(m, x[c]);
            }
            float ls = 0.0f;
#pragma unroll
            for (int c = 0; c < 4; ++c) ls += ok[c] ? __expf(x[c] - m) : 0.0f;
            // merge (m,l) across the 16 lanes holding this row's columns
#pragma unroll
            for (int off = 1; off < 16; off <<= 1) {
                const float mo = __shfl_xor(m, off, 64);
                const float lo = __shfl_xor(ls, off, 64);
                const float M  = fmaxf(m, mo);
                const float e1 = (ls > 0.0f) ? ls * __expf(m - M) : 0.0f;
                const float e2 = (lo > 0.0f) ? lo * __expf(mo - M) : 0.0f;
                m = M; ls = e1 + e2;
            }
            if (lm == 0) { mpart[wc][r] = m; lpart[wc][r] = ls; }
        }
    }
    __syncthreads();
    {   // all 512 threads: merge the 2 col-wave partials for row tid
        float m = -INFINITY, lsum = 0.0f;
#pragma unroll
        for (int p = 0; p < 2; ++p) {
            const float mp = mpart[p][tid];
            const float lp = lpart[p][tid];
            if (lp > 0.0f) {
                if (mp > m) { lsum = lsum * __expf(m - mp) + lp; m = mp; }
                else        { lsum += lp * __expf(mp - m); }
            }
        }
        const int idx = (bb * SEQLEN + tid) * NCHUNK + chunk;
        pm[idx] = m;
        pl[idx] = lsum;
    }
}

// ---- combine: merge 8 partial (m,l) + true logit -> per-block loss sums ----
__global__ __launch_bounds__(256) void combine_kernel(
    const float* __restrict__ pm, const float* __restrict__ pl,
    const float* __restrict__ tlw, float* __restrict__ bsum)
{
    __shared__ float wsum[4];
    const int tid = threadIdx.x;
    const int w = tid >> 6, lane = tid & 63;
    const int idx = blockIdx.x * 256 + tid;      // 0..16383
    float m = -INFINITY, l = 0.0f;
#pragma unroll
    for (int c = 0; c < NCHUNK; ++c) {
        const float mp = pm[idx * NCHUNK + c];
        const float lp = pl[idx * NCHUNK + c];
        if (lp > 0.0f) {
            if (mp > m) { l = l * __expf(m - mp) + lp; m = mp; }
            else        { l += lp * __expf(mp - m); }
        }
    }
    const float t = tlw[idx];
    const float M = fmaxf(m, t);
    float loss = __logf(l * __expf(m - M) + __expf(t - M)) + M - t;
#pragma unroll
    for (int off = 32; off > 0; off >>= 1) loss += __shfl_xor(loss, off, 64);
    if (lane == 0) wsum[w] = loss;
    __syncthreads();
    if (tid == 0) bsum[blockIdx.x] = wsum[0] + wsum[1] + wsum[2] + wsum[3];
}

__global__ void finalize_kernel(const float* __restrict__ bsum, float* __restrict__ out) {
    float v = bsum[threadIdx.x];
#pragma unroll
    for (int off = 32; off > 0; off >>= 1) v += __shfl_xor(v, off, 64);
    if (threadIdx.x == 0) out[0] = v * (0.5f / (float)(BATCH * SEQLEN));
}

extern "C" void kernel_launch(void* const* d_in, const int* in_sizes, int n_in,
                              void* d_out, int out_size, void* d_ws, size_t ws_size,
                              hipStream_t stream) {
    const float* h      = (const float*)d_in[0];
    const int*   labels = (const int*)d_in[1];
    const int*   sids   = (const int*)d_in[2];
    const float* W      = (const float*)d_in[3];
    const float* bias   = (const float*)d_in[4];

    // workspace layout (~34.7 MB, 16B-aligned offsets)
    char* base = (char*)d_ws;
    unsigned short* hb = (unsigned short*)base;                 // 33,554,432
    float* tlw  = (float*)(base + 33554432);                    //     65,536
    float* pmw  = (float*)(base + 33619968);                    //    524,288
    float* plw  = (float*)(base + 34144256);                    //    524,288
    float* bsum = (float*)(base + 34668544);                    //        256

    prep_kernel<<<dim3(4096), dim3(256), 0, stream>>>(h, labels, W, bias, hb, tlw);
    sampled_softmax_main<<<dim3(256), dim3(512), 0, stream>>>(
        labels, sids, hb, W, bias, pmw, plw);
    combine_kernel<<<dim3(64), dim3(256), 0, stream>>>(pmw, plw, tlw, bsum);
    finalize_kernel<<<dim3(1), dim3(64), 0, stream>>>(bsum, (float*)d_out);
}